// Round 3
// baseline (283.603 us; speedup 1.0000x reference)
//
#include <hip/hip_runtime.h>
#include <hip/hip_bf16.h>
#include <stdint.h>

// CrossAttention: B=8, C=256, H=W=64 (N=4096), CR=64.
// Stage 1: proj -> Qb [B][N][64] bf16 (pre-scaled by log2(e)), Kb [B][N][64] bf16,
//          Vb [B][C][N] bf16 (+bias)
// Stage 2: flash-attn, QBLK=64, KVBLK=64, 4 waves:
//   - K operands in registers (double-buffered global prefetch)
//   - V in LDS (double-buffered, global_load_lds w/ pre-swizzled source)
//   - shared P in LDS (chunk-XOR swizzle, conflict-free), channel-split PV
//   - defer-max online softmax (THR=8 in log2 domain), exp2, cvt_pk_bf16

#define B_ 8
#define C_ 256
#define N_ 4096
#define CR_ 64

typedef unsigned short u16;
typedef __attribute__((ext_vector_type(8))) __bf16 bf16x8;
typedef __attribute__((ext_vector_type(8))) unsigned short ushort8;
typedef __attribute__((ext_vector_type(4))) float f32x4;

__device__ __forceinline__ u16 f2bf(float f) {
  union { float f; unsigned int u; } v; v.f = f;
  unsigned int r = (v.u + 0x7fffu + ((v.u >> 16) & 1u)) >> 16;
  return (u16)r;
}
__device__ __forceinline__ unsigned int cvtpk(float a, float b) {
  unsigned int r;
  asm("v_cvt_pk_bf16_f32 %0, %1, %2" : "=v"(r) : "v"(a), "v"(b));
  return r;
}

typedef __attribute__((address_space(1))) const unsigned int gu32_t;
typedef __attribute__((address_space(3))) unsigned int lu32_t;
__device__ __forceinline__ void gll16(const void* g, void* l) {
  __builtin_amdgcn_global_load_lds((gu32_t*)g, (lu32_t*)l, 16, 0, 0);
}

// ---------------- Projection kernel (round-2 structure + log2e fold on Q) ----
// grid (8, B, 12): role 0-1 -> Q chunks, 2-3 -> K chunks, 4-11 -> V chunks.
__global__ __launch_bounds__(256) void proj_kernel(
    const float* __restrict__ src, const float* __restrict__ gui,
    const float* __restrict__ Wq, const float* __restrict__ Wk,
    const float* __restrict__ Wv, const float* __restrict__ bv,
    u16* __restrict__ Qb, u16* __restrict__ Kb, u16* __restrict__ Vb)
{
  __shared__ float Wl[32 * 256];
  const int t = threadIdx.x;
  const int b = blockIdx.y;
  const int role = blockIdx.z;
  const int px0 = blockIdx.x * 512;

  const float* W;
  const float* in;
  if (role < 2)      { W = Wq + (size_t)role * 32 * 256;       in = src; }
  else if (role < 4) { W = Wk + (size_t)(role - 2) * 32 * 256; in = gui; }
  else               { W = Wv + (size_t)(role - 4) * 32 * 256; in = gui; }

#pragma unroll
  for (int i = 0; i < 32; ++i) Wl[i * 256 + t] = W[i * 256 + t];
  __syncthreads();

  float acc0[32], acc1[32];
#pragma unroll
  for (int q = 0; q < 32; ++q) { acc0[q] = 0.f; acc1[q] = 0.f; }

  const float* inb = in + (size_t)b * C_ * N_ + px0 + t;
  for (int c0 = 0; c0 < 256; c0 += 8) {
    float s0[8], s1[8];
#pragma unroll
    for (int j = 0; j < 8; ++j) {
      s0[j] = inb[(size_t)(c0 + j) * N_];
      s1[j] = inb[(size_t)(c0 + j) * N_ + 256];
    }
#pragma unroll
    for (int q = 0; q < 32; ++q) {
      const float* wr = &Wl[q * 256 + c0];
#pragma unroll
      for (int j = 0; j < 8; ++j) {
        acc0[q] = fmaf(wr[j], s0[j], acc0[q]);
        acc1[q] = fmaf(wr[j], s1[j], acc1[q]);
      }
    }
  }

  if (role < 4) {
    u16* dst = (role < 2) ? Qb : Kb;
    const float scl = (role < 2) ? 1.44269504f : 1.0f;  // fold log2e into Q
    const int cbase = (role & 1) * 32;
#pragma unroll
    for (int h = 0; h < 2; ++h) {
      const float* ap = h ? acc1 : acc0;
      u16* op = dst + ((size_t)(b * N_ + px0 + h * 256 + t)) * CR_ + cbase;
#pragma unroll
      for (int g4 = 0; g4 < 4; ++g4) {
        ushort8 pk;
#pragma unroll
        for (int j = 0; j < 8; ++j) pk[j] = f2bf(ap[g4 * 8 + j] * scl);
        *reinterpret_cast<ushort8*>(op + g4 * 8) = pk;
      }
    }
  } else {
    const int v0 = (role - 4) * 32;
#pragma unroll
    for (int q = 0; q < 32; ++q) {
      float bq = bv[v0 + q];
      u16* op = Vb + ((size_t)(b * C_ + v0 + q)) * N_ + px0 + t;
      op[0] = f2bf(acc0[q] + bq);
      op[256] = f2bf(acc1[q] + bq);
    }
  }
}

// ---------------- Flash attention kernel ----------------
// LDS map: [0,32768) Vbuf0; [32768,65536) Vbuf1; [65536,73728) P [64q][128B];
// [73728,73984) scales f32[64]; [73984,74000) flags f32[4].
// Epilogue: per-wave transpose tile, base = wave*16896 (clobbers V/P, not SC).
#define VB1 32768
#define PB  65536
#define SCO 73728
#define FLO 73984

__global__ __launch_bounds__(256, 2) void attn_kernel(
    const u16* __restrict__ Qb, const u16* __restrict__ Kb, const u16* __restrict__ Vb,
    const float* __restrict__ source, const float* __restrict__ gamma,
    float* __restrict__ out)
{
  __shared__ uint4 smem4[4688];  // 75008 B
  char* smem = (char*)smem4;

  const int t = threadIdx.x;
  const int lane = t & 63;
  const int wave = t >> 6;
  const int lg = lane >> 4;
  const int lm = lane & 15;
  const int b = blockIdx.y;
  const int q0 = blockIdx.x * 64;
  const int sw = lm & 7;

  // Q fragments (B-operand of swapped S): q-row = q0 + 16*wave + lm
  bf16x8 aq[2];
  {
    const u16* qp = Qb + ((size_t)(b * N_ + q0 + wave * 16 + lm)) * CR_ + lg * 8;
    aq[0] = *reinterpret_cast<const bf16x8*>(qp);
    aq[1] = *reinterpret_cast<const bf16x8*>(qp + 32);
  }

  const u16* KbT = Kb + (size_t)b * N_ * CR_;
  const char* VbB = (const char*)(Vb + (size_t)b * C_ * N_);

  // V staging source offsets (pre-swizzled global, linear LDS dest)
  const int srow = t >> 3, cslot = t & 7;
  unsigned int vgo[8];
#pragma unroll
  for (int i = 0; i < 8; ++i) {
    int row = i * 32 + srow;
    int cl = cslot ^ (row & 7);
    vgo[i] = (unsigned int)((row * N_ + cl * 8) * 2);
  }

  f32x4 accv[4][4];
  const f32x4 zero4 = {0.f, 0.f, 0.f, 0.f};
#pragma unroll
  for (int i = 0; i < 4; ++i)
#pragma unroll
    for (int j = 0; j < 4; ++j) accv[i][j] = zero4;
  float mrow = -1e30f, lrow = 0.f;

  bf16x8 kA[8], kB[8];

#define LOADK(KREG, KTILE) do {                                              \
    const u16* kb_ = KbT + (size_t)(KTILE) * (64 * CR_);                     \
    _Pragma("unroll")                                                        \
    for (int f = 0; f < 8; ++f)                                              \
      KREG[f] = *reinterpret_cast<const bf16x8*>(                            \
          kb_ + ((f >> 1) * 16 + lm) * CR_ + (f & 1) * 32 + lg * 8);         \
  } while (0)

#define STAGEV(KTILE, VOFF) do {                                             \
    unsigned int vadd_ = (unsigned int)((KTILE) * 128);                      \
    _Pragma("unroll")                                                        \
    for (int i = 0; i < 8; ++i)                                              \
      gll16(VbB + vgo[i] + vadd_, smem + (VOFF) + i * 4096 + wave * 1024);   \
  } while (0)

  // prologue: tile 0 in flight
  STAGEV(0, 0);
  LOADK(kA, 0);

#define STEP(KT, KC, KN, VCUR, VNXT) do {                                    \
    const int ktn_ = ((KT) + 1 < 64) ? (KT) + 1 : 63;                        \
    STAGEV(ktn_, VNXT);                                                      \
    LOADK(KN, ktn_);                                                         \
    /* S^T = mfma(A=K, B=Q): lane holds S[key=kf*16+lg*4+r][q=16w+lm] */     \
    f32x4 sf[4];                                                             \
    _Pragma("unroll")                                                        \
    for (int kf = 0; kf < 4; ++kf) {                                         \
      sf[kf] = zero4;                                                        \
      sf[kf] = __builtin_amdgcn_mfma_f32_16x16x32_bf16(KC[kf*2], aq[0], sf[kf], 0, 0, 0); \
      sf[kf] = __builtin_amdgcn_mfma_f32_16x16x32_bf16(KC[kf*2+1], aq[1], sf[kf], 0, 0, 0); \
    }                                                                        \
    float v_ = sf[0][0];                                                     \
    _Pragma("unroll")                                                        \
    for (int kf = 0; kf < 4; ++kf)                                           \
      _Pragma("unroll")                                                      \
      for (int r = 0; r < 4; ++r) v_ = fmaxf(v_, sf[kf][r]);                 \
    v_ = fmaxf(v_, __shfl_xor(v_, 16));                                      \
    v_ = fmaxf(v_, __shfl_xor(v_, 32));                                      \
    const bool nres_ = !__all(v_ <= mrow + 8.0f);                            \
    float sc_ = 1.f;                                                         \
    if (nres_) {                                                             \
      float mn_ = fmaxf(mrow, v_);                                           \
      sc_ = exp2f(mrow - mn_);                                               \
      mrow = mn_;                                                            \
    }                                                                        \
    float s_ = 0.f;                                                          \
    _Pragma("unroll")                                                        \
    for (int kf = 0; kf < 4; ++kf)                                           \
      _Pragma("unroll")                                                      \
      for (int r = 0; r < 4; ++r) {                                          \
        float e_ = exp2f(sf[kf][r] - mrow);                                  \
        sf[kf][r] = e_;                                                      \
        s_ += e_;                                                            \
      }                                                                      \
    s_ += __shfl_xor(s_, 16);                                                \
    s_ += __shfl_xor(s_, 32);                                                \
    lrow = lrow * sc_ + s_;                                                  \
    /* P write: row=16w+lm, chunk-XOR swizzle */                             \
    {                                                                        \
      char* prow_ = smem + PB + (wave * 16 + lm) * 128;                      \
      _Pragma("unroll")                                                      \
      for (int kf = 0; kf < 4; ++kf) {                                       \
        uint2 w2_;                                                           \
        w2_.x = cvtpk(sf[kf][0], sf[kf][1]);                                 \
        w2_.y = cvtpk(sf[kf][2], sf[kf][3]);                                 \
        *reinterpret_cast<uint2*>(                                           \
            prow_ + (((kf * 2 + (lg >> 1)) ^ sw) << 4) + ((lg & 1) << 3)) = w2_; \
      }                                                                      \
    }                                                                        \
    if (lg == 0) *(float*)(smem + SCO + (wave * 16 + lm) * 4) = sc_;         \
    if (lane == 0) *(float*)(smem + FLO + wave * 4) = nres_ ? 1.f : 0.f;     \
    __syncthreads();  /* (a): P, scales, flags visible; V(KT) drained */     \
    /* rescale accv (rows rb*16+lg*4+r) if owning wave rescaled */           \
    {                                                                        \
      f32x4 fl_ = *reinterpret_cast<const f32x4*>(smem + FLO);               \
      if (fl_[0] + fl_[1] + fl_[2] + fl_[3] > 0.f) {                         \
        _Pragma("unroll")                                                    \
        for (int rb = 0; rb < 4; ++rb) {                                     \
          if (fl_[rb] > 0.f) {                                               \
            f32x4 s4_ = *reinterpret_cast<const f32x4*>(                     \
                smem + SCO + (rb * 16 + lg * 4) * 4);                        \
            _Pragma("unroll")                                                \
            for (int cf = 0; cf < 4; ++cf)                                   \
              _Pragma("unroll")                                              \
              for (int r = 0; r < 4; ++r) accv[rb][cf][r] *= s4_[r];         \
          }                                                                  \
        }                                                                    \
      }                                                                      \
    }                                                                        \
    /* PV channel-split: wave handles ch 64*wave + cf*16+lm, all 64 q */     \
    _Pragma("unroll")                                                        \
    for (int kk = 0; kk < 2; ++kk) {                                         \
      bf16x8 pa_[4], vb_[4];                                                 \
      _Pragma("unroll")                                                      \
      for (int rb = 0; rb < 4; ++rb)                                         \
        pa_[rb] = *reinterpret_cast<const bf16x8*>(                          \
            smem + PB + (rb * 16 + lm) * 128 + (((kk * 4 + lg) ^ sw) << 4)); \
      _Pragma("unroll")                                                      \
      for (int cf = 0; cf < 4; ++cf)                                         \
        vb_[cf] = *reinterpret_cast<const bf16x8*>(                          \
            smem + (VCUR) + (wave * 64 + cf * 16 + lm) * 128 +               \
            (((kk * 4 + lg) ^ sw) << 4));                                    \
      _Pragma("unroll")                                                      \
      for (int rb = 0; rb < 4; ++rb)                                         \
        _Pragma("unroll")                                                    \
        for (int cf = 0; cf < 4; ++cf)                                       \
          accv[rb][cf] = __builtin_amdgcn_mfma_f32_16x16x32_bf16(            \
              pa_[rb], vb_[cf], accv[rb][cf], 0, 0, 0);                      \
    }                                                                        \
    __syncthreads();  /* (b): safe to overwrite V(KT) region */              \
  } while (0)

  for (int kt2 = 0; kt2 < 64; kt2 += 2) {
    STEP(kt2,     kA, kB, 0,   VB1);
    STEP(kt2 + 1, kB, kA, VB1, 0);
  }

  // ---- epilogue ----
  const float g = gamma[0];
  if (lg == 0) *(float*)(smem + SCO + (wave * 16 + lm) * 4) = g / lrow;
  __syncthreads();

  f32x4 il[4];
#pragma unroll
  for (int rb = 0; rb < 4; ++rb)
    il[rb] = *reinterpret_cast<const f32x4*>(smem + SCO + (rb * 16 + lg * 4) * 4);

  // per-wave transpose tile [64 q][66 f32 stride], base = wave*16896
  char* tlb = smem + wave * 16896;
#pragma unroll
  for (int rb = 0; rb < 4; ++rb)
#pragma unroll
    for (int cf = 0; cf < 4; ++cf)
#pragma unroll
      for (int r = 0; r < 4; ++r)
        *(float*)(tlb + (((rb * 16 + lg * 4 + r) * 66 + cf * 16 + lm) << 2)) =
            accv[rb][cf][r] * il[rb][r];

  // wave-local: write out[b][64*wave + c][q0 + lane] (+ source)
  for (int c = 0; c < 64; ++c) {
    float val = *(const float*)(tlb + ((lane * 66 + c) << 2));
    size_t gi = ((size_t)(b * C_) + wave * 64 + c) * N_ + q0 + lane;
    out[gi] = val + source[gi];
  }
}

extern "C" void kernel_launch(void* const* d_in, const int* in_sizes, int n_in,
                              void* d_out, int out_size, void* d_ws, size_t ws_size,
                              hipStream_t stream) {
  const float* src = (const float*)d_in[0];
  const float* gui = (const float*)d_in[1];
  const float* Wq  = (const float*)d_in[2];
  const float* Wk  = (const float*)d_in[3];
  const float* Wv  = (const float*)d_in[4];
  const float* bv  = (const float*)d_in[5];
  const float* gm  = (const float*)d_in[6];
  float* out = (float*)d_out;

  u16* Qb = (u16*)d_ws;                         // 4 MB
  u16* Kb = Qb + (size_t)B_ * N_ * CR_;         // 4 MB
  u16* Vb = Kb + (size_t)B_ * N_ * CR_;         // 16 MB

  proj_kernel<<<dim3(8, B_, 12), dim3(256), 0, stream>>>(src, gui, Wq, Wk, Wv, bv, Qb, Kb, Vb);
  attn_kernel<<<dim3(N_ / 64, B_), dim3(256), 0, stream>>>(Qb, Kb, Vb, src, gm, out);
}